// Round 3
// baseline (342.143 us; speedup 1.0000x reference)
//
#include <hip/hip_runtime.h>
#include <math.h>

typedef unsigned short u16;
typedef unsigned int   u32;

typedef __attribute__((ext_vector_type(8))) _Float16 f16x8;
typedef __attribute__((ext_vector_type(4))) float    f32x4;

// ---------- constants ----------
#define NB   2
#define C    256
#define H    96
#define W    96
#define HW   (H*W)          // 9216
#define HP   98
#define OC   256
#define KK   9              // 3x3 taps
#define KDIM (KK*C)         // 2304
#define NS   (NB*HW)        // 18432 spatial columns
#define NCHUNK 8            // channel chunks in stage-A conv

// ws layout (bytes)
#define PARTIAL_OFF  0                          // 8*2*21*9216 fp32  = 12386304
#define OFFBUF_OFF   12386304                   // 2*18*9216 fp32    = 1327104
#define AD2_OFF      13713408                   // 2*3*9216 fp32     = 221184
#define XP_OFF       13934592                   // 2*98*98*256 fp32  = 19668992
#define AHI_OFF      33603584                   // 256*2304 f16      = 1179648
#define ALO_OFF      34783232                   // 256*2304 f16      = 1179648
#define IDX_OFF      35962880                   // 9*18432*4 int     = 2654208
#define G_OFF        38617088                   // 9*18432*4 fp32    = 2654208
#define WS_NEED      41271296

__device__ __forceinline__ u16 h2u(_Float16 h) {
  return __builtin_bit_cast(unsigned short, h);
}
__device__ __forceinline__ void split16(float v, u16& hi, u16& lo) {
  _Float16 h = (_Float16)v;        // v_cvt_f16_f32, RNE
  float r = v - (float)h;          // exact residual (Sterbenz)
  _Float16 l = (_Float16)r;
  hi = h2u(h); lo = h2u(l);
}

// ---------- stage A: 21-channel 3x3 conv over 256c, fp32, c split into 8 chunks ----------
// grid 576 = n(2) * tile(36 of 16x16) * chunk(8); block 64 (1 wave), 4 outputs/thread
__global__ __launch_bounds__(64) void conv_small(
    const float* __restrict__ x, const float* __restrict__ w_p,
    const float* __restrict__ w_ad, float* __restrict__ partial) {
  __shared__ float wsm[32*21*9];
  int bx = blockIdx.x;
  int chunk = bx & 7;
  int r  = bx >> 3;
  int tile = r % 36;
  int n    = r / 36;
  int h0 = (tile / 6) * 16, w0 = (tile % 6) * 16;
  int c0 = chunk * 32;
  int tid = threadIdx.x;

  for (int idx = tid; idx < 32*21*9; idx += 64) {
    int cc = idx / 189; int rem = idx % 189; int ch = rem / 9; int tap = rem % 9;
    int gc = c0 + cc;
    wsm[idx] = (ch < 18) ? w_p[(ch*C + gc)*9 + tap] : w_ad[((ch-18)*C + gc)*9 + tap];
  }
  __syncthreads();

  int row = tid >> 2;          // 0..15
  int wq  = tid & 3;           // 0..3
  int h  = h0 + row;
  int wb = w0 + wq * 4;

  float acc[21][4];
  #pragma unroll
  for (int ch = 0; ch < 21; ch++)
    { acc[ch][0]=0.f; acc[ch][1]=0.f; acc[ch][2]=0.f; acc[ch][3]=0.f; }

  const float* xn = x + (size_t)(n*C + c0) * HW;
  for (int cc = 0; cc < 32; cc++) {
    const float* xc = xn + cc * HW;
    float xr[3][6];
    #pragma unroll
    for (int di = 0; di < 3; di++) {
      int hg = h + di - 1;
      bool hok = ((unsigned)hg < 96u);
      #pragma unroll
      for (int jj = 0; jj < 6; jj++) {
        int wg = wb + jj - 1;
        bool ok = hok && ((unsigned)wg < 96u);
        xr[di][jj] = ok ? xc[hg*W + wg] : 0.f;
      }
    }
    const float* wsc = wsm + cc * 189;
    #pragma unroll
    for (int ch = 0; ch < 21; ch++) {
      const float* wv = wsc + ch * 9;
      #pragma unroll
      for (int di = 0; di < 3; di++)
        #pragma unroll
        for (int dj = 0; dj < 3; dj++) {
          float wgt = wv[di*3 + dj];
          #pragma unroll
          for (int j = 0; j < 4; j++)
            acc[ch][j] = fmaf(xr[di][dj + j], wgt, acc[ch][j]);
        }
    }
  }
  #pragma unroll
  for (int ch = 0; ch < 21; ch++) {
    int off = ((chunk*2 + n)*21 + ch)*HW + h*W + wb;
    *(float4*)(partial + off) = make_float4(acc[ch][0], acc[ch][1], acc[ch][2], acc[ch][3]);
  }
}

// ---------- reduce partials, add bias, sigmoid for ad ----------
__global__ __launch_bounds__(256) void reduce_small(
    const float* __restrict__ partial, const float* __restrict__ b_p,
    const float* __restrict__ b_ad, float* __restrict__ off_buf,
    float* __restrict__ ad2_buf) {
  int e = blockIdx.x * 256 + threadIdx.x;
  if (e >= NB*21*HW) return;
  int n  = e / (21*HW);
  int r  = e % (21*HW);
  int ch = r / HW;
  int hw = r % HW;
  float s = 0.f;
  #pragma unroll
  for (int chunk = 0; chunk < NCHUNK; chunk++)
    s += partial[((chunk*2 + n)*21 + ch)*HW + hw];
  if (ch < 18) {
    off_buf[(n*18 + ch)*HW + hw] = s + b_p[ch];
  } else {
    float z = s + b_ad[ch - 18];
    ad2_buf[(n*3 + (ch-18))*HW + hw] = 2.0f / (1.0f + expf(z));   // (1-sigmoid(z))*DIL
  }
}

// ---------- NCHW fp32 -> padded NHWC fp32 (borders pre-zeroed by memset) ----------
// grid 1152 = n(2) * cb(4 of 64c) * hwb(144 of 64); block 256
__global__ __launch_bounds__(256) void pad_pack(
    const float* __restrict__ x, float* __restrict__ xp) {
  __shared__ float ts[64][65];
  int bx = blockIdx.x;
  int n = bx / 576; int r = bx % 576;
  int cb = r / 144; int hwb = r % 144;
  int c0 = cb * 64, hw0 = hwb * 64;
  int tid = threadIdx.x;
  int ii = tid & 63; int cl4 = tid >> 6;
  #pragma unroll
  for (int r2 = 0; r2 < 16; r2++) {
    int c_l = cl4*16 + r2;
    ts[c_l][ii] = x[(size_t)(n*C + c0 + c_l)*HW + hw0 + ii];
  }
  __syncthreads();
  int hw = hw0 + ii;
  int h = hw / W, w = hw % W;
  // BUG FIX (r2->r3): destination channel offset must include c0 (= cb*64).
  float* dst = xp + ((size_t)(n*HP + h + 1)*HP + (w + 1))*C + c0 + cl4*16;
  #pragma unroll
  for (int q = 0; q < 4; q++) {
    *(float4*)(dst + q*4) = make_float4(ts[cl4*16 + q*4 + 0][ii], ts[cl4*16 + q*4 + 1][ii],
                                        ts[cl4*16 + q*4 + 2][ii], ts[cl4*16 + q*4 + 3][ii]);
  }
}

// ---------- repack + split w_conv [o][c][k] -> A_hi/A_lo [o][k*256+c] f16 ----------
__global__ __launch_bounds__(256) void pack_A(
    const float* __restrict__ w_conv, u16* __restrict__ A_hi, u16* __restrict__ A_lo) {
  int e = blockIdx.x * 256 + threadIdx.x;      // < 256*2304
  int o = e / KDIM; int r = e % KDIM; int k = r >> 8; int c = r & 255;
  float a = w_conv[(o*C + c)*9 + k];
  u16 hi, lo; split16(a, hi, lo);
  A_hi[e] = hi; A_lo[e] = lo;
}

// ---------- bilinear taps: 4 indices + 4 weights per (s, k) ----------
__global__ __launch_bounds__(256) void make_taps(
    const float* __restrict__ off_buf, const float* __restrict__ ad2_buf,
    int* __restrict__ idx_arr, float* __restrict__ g_arr) {
  int e = blockIdx.x * 256 + threadIdx.x;      // < 9*18432
  int k = e / NS; int s = e % NS;
  int n = s / HW; int hw = s % HW;
  int h = hw / W, w = hw % W;
  float ri = (float)(k / 3) - 1.0f, rj = (float)(k % 3) - 1.0f;
  float offx = off_buf[(n*18 + k)*HW + hw];
  float offy = off_buf[(n*18 + k + 9)*HW + hw];
  float a2   = ad2_buf[(n*3 + (k % 3))*HW + hw];
  float px = (float)(h + 1) + ri + offx + a2 * ri;
  float py = (float)(w + 1) + rj + offy + a2 * rj;
  float fx = floorf(px), fy = floorf(py);
  int qltx = min(max((int)fx, 0), 97);
  int qlty = min(max((int)fy, 0), 97);
  int qrbx = min(max((int)fx + 1, 0), 97);
  int qrby = min(max((int)fy + 1, 0), 97);
  bool mx = (px < 1.0f) || (px > 96.0f);
  bool my = (py < 1.0f) || (py > 96.0f);
  float pxm = mx ? fx : px;
  float pym = my ? fy : py;
  pxm = fminf(fmaxf(pxm, 0.f), 97.f);
  pym = fminf(fmaxf(pym, 0.f), 97.f);
  float glx = 1.0f + ((float)qltx - pxm);
  float grx = 1.0f - ((float)qrbx - pxm);
  float gly = 1.0f + ((float)qlty - pym);
  float gry = 1.0f - ((float)qrby - pym);
  int base = n * HP * HP * C;
  int4 qi;
  qi.x = base + (qltx*HP + qlty)*C;   // lt
  qi.y = base + (qrbx*HP + qrby)*C;   // rb
  qi.z = base + (qltx*HP + qrby)*C;   // lb  (lt_x, rb_y)
  qi.w = base + (qrbx*HP + qlty)*C;   // rt  (rb_x, lt_y)
  float4 gg = make_float4(glx*gly, grx*gry, glx*gry, grx*gly);
  *(int4*)(idx_arr + (size_t)e*4) = qi;
  *(float4*)(g_arr  + (size_t)e*4) = gg;
}

// ---------- fused gather + split-f16 MFMA GEMM ----------
// C[o,s] = sum_kc A[o,kc]*B[kc,s]; A,B each split hi+lo f16; D += Ah*Bh + Ah*Bl + Al*Bh.
// grid 576 = mo(2: 128 o) * sb(288: 64 s); block 256 (4 waves, each 64o x 32s)
__global__ __launch_bounds__(256) void gemm_def(
    const u16* __restrict__ A_hi, const u16* __restrict__ A_lo,
    const float* __restrict__ xp,
    const int* __restrict__ idx_arr, const float* __restrict__ g_arr,
    float* __restrict__ out) {
  __shared__ u16 Ah[128*40];
  __shared__ u16 Al[128*40];
  __shared__ u16 Bh[64*40];
  __shared__ u16 Bl[64*40];
  int bx = blockIdx.x;
  int mo = bx & 1; int sb = bx >> 1;
  int o0 = mo * 128; int s0 = sb * 64;
  int n = s0 / HW; int hw0 = s0 % HW;
  int tid = threadIdx.x;
  int wave = tid >> 6, lane = tid & 63;
  int l16 = lane & 15, quad = lane >> 4;
  int mw = wave >> 1, nw = wave & 1;

  f32x4 acc[4][2];
  f32x4 z4 = {0.f, 0.f, 0.f, 0.f};
  #pragma unroll
  for (int i = 0; i < 4; i++)
    { acc[i][0] = z4; acc[i][1] = z4; }

  int arow = tid >> 1; int acs = (tid & 1) * 16;
  const u16* agh = A_hi + (size_t)(o0 + arow) * KDIM + acs;
  const u16* agl = A_lo + (size_t)(o0 + arow) * KDIM + acs;
  int s_l = tid >> 2; int cs = (tid & 3) * 8;
  int sg = s0 + s_l;

  for (int it = 0; it < 72; it++) {
    int kbase = it * 32;
    int k   = it >> 3;
    int c0k = (it & 7) * 32;
    // global loads issued early
    uint4 a0h = *(const uint4*)(agh + kbase);
    uint4 a1h = *(const uint4*)(agh + kbase + 8);
    uint4 a0l = *(const uint4*)(agl + kbase);
    uint4 a1l = *(const uint4*)(agl + kbase + 8);
    int4   qi = *(const int4*)(idx_arr + (size_t)(k*NS + sg)*4);
    float4 gg = *(const float4*)(g_arr  + (size_t)(k*NS + sg)*4);
    const float* p0 = xp + qi.x + c0k + cs;
    const float* p1 = xp + qi.y + c0k + cs;
    const float* p2 = xp + qi.z + c0k + cs;
    const float* p3 = xp + qi.w + c0k + cs;
    float4 t0a = *(const float4*)(p0), t0b = *(const float4*)(p0 + 4);
    float4 t1a = *(const float4*)(p1), t1b = *(const float4*)(p1 + 4);
    float4 t2a = *(const float4*)(p2), t2b = *(const float4*)(p2 + 4);
    float4 t3a = *(const float4*)(p3), t3b = *(const float4*)(p3 + 4);
    float v[8];
    v[0] = gg.x*t0a.x + gg.y*t1a.x + gg.z*t2a.x + gg.w*t3a.x;
    v[1] = gg.x*t0a.y + gg.y*t1a.y + gg.z*t2a.y + gg.w*t3a.y;
    v[2] = gg.x*t0a.z + gg.y*t1a.z + gg.z*t2a.z + gg.w*t3a.z;
    v[3] = gg.x*t0a.w + gg.y*t1a.w + gg.z*t2a.w + gg.w*t3a.w;
    v[4] = gg.x*t0b.x + gg.y*t1b.x + gg.z*t2b.x + gg.w*t3b.x;
    v[5] = gg.x*t0b.y + gg.y*t1b.y + gg.z*t2b.y + gg.w*t3b.y;
    v[6] = gg.x*t0b.z + gg.y*t1b.z + gg.z*t2b.z + gg.w*t3b.z;
    v[7] = gg.x*t0b.w + gg.y*t1b.w + gg.z*t2b.w + gg.w*t3b.w;
    u16 hb[8], lb[8];
    #pragma unroll
    for (int j = 0; j < 8; j++) split16(v[j], hb[j], lb[j]);
    __syncthreads();                       // prior MFMA frag reads done
    *(uint4*)(Ah + arow*40 + acs)     = a0h;
    *(uint4*)(Ah + arow*40 + acs + 8) = a1h;
    *(uint4*)(Al + arow*40 + acs)     = a0l;
    *(uint4*)(Al + arow*40 + acs + 8) = a1l;
    uint4 bph, bpl;
    bph.x = (u32)hb[0] | ((u32)hb[1] << 16); bph.y = (u32)hb[2] | ((u32)hb[3] << 16);
    bph.z = (u32)hb[4] | ((u32)hb[5] << 16); bph.w = (u32)hb[6] | ((u32)hb[7] << 16);
    bpl.x = (u32)lb[0] | ((u32)lb[1] << 16); bpl.y = (u32)lb[2] | ((u32)lb[3] << 16);
    bpl.z = (u32)lb[4] | ((u32)lb[5] << 16); bpl.w = (u32)lb[6] | ((u32)lb[7] << 16);
    *(uint4*)(Bh + s_l*40 + cs) = bph;
    *(uint4*)(Bl + s_l*40 + cs) = bpl;
    __syncthreads();
    f16x8 afh[4], afl[4], bfh[2], bfl[2];
    #pragma unroll
    for (int mi = 0; mi < 4; mi++) {
      int rr = (mw*64 + mi*16 + l16)*40 + quad*8;
      afh[mi] = *(const f16x8*)(Ah + rr);
      afl[mi] = *(const f16x8*)(Al + rr);
    }
    #pragma unroll
    for (int ni = 0; ni < 2; ni++) {
      int rr = (nw*32 + ni*16 + l16)*40 + quad*8;
      bfh[ni] = *(const f16x8*)(Bh + rr);
      bfl[ni] = *(const f16x8*)(Bl + rr);
    }
    #pragma unroll
    for (int mi = 0; mi < 4; mi++)
      #pragma unroll
      for (int ni = 0; ni < 2; ni++) {
        acc[mi][ni] = __builtin_amdgcn_mfma_f32_16x16x32_f16(afh[mi], bfh[ni], acc[mi][ni], 0, 0, 0);
        acc[mi][ni] = __builtin_amdgcn_mfma_f32_16x16x32_f16(afh[mi], bfl[ni], acc[mi][ni], 0, 0, 0);
        acc[mi][ni] = __builtin_amdgcn_mfma_f32_16x16x32_f16(afl[mi], bfh[ni], acc[mi][ni], 0, 0, 0);
      }
  }
  #pragma unroll
  for (int mi = 0; mi < 4; mi++)
    #pragma unroll
    for (int ni = 0; ni < 2; ni++) {
      int hw = hw0 + nw*32 + ni*16 + l16;
      #pragma unroll
      for (int rr = 0; rr < 4; rr++) {
        int o = o0 + mw*64 + mi*16 + quad*4 + rr;
        out[(size_t)(n*OC + o)*HW + hw] = acc[mi][ni][rr];
      }
    }
}

extern "C" void kernel_launch(void* const* d_in, const int* in_sizes, int n_in,
                              void* d_out, int out_size, void* d_ws, size_t ws_size,
                              hipStream_t stream) {
  const float* x      = (const float*)d_in[0];
  const float* w_p    = (const float*)d_in[1];
  const float* b_p    = (const float*)d_in[2];
  const float* w_ad   = (const float*)d_in[3];
  const float* b_ad   = (const float*)d_in[4];
  const float* w_conv = (const float*)d_in[5];
  float* out = (float*)d_out;

  char* ws = (char*)d_ws;
  float* partial = (float*)(ws + PARTIAL_OFF);
  float* off_buf = (float*)(ws + OFFBUF_OFF);
  float* ad2_buf = (float*)(ws + AD2_OFF);
  float* xp      = (float*)(ws + XP_OFF);
  u16*   A_hi    = (u16*)  (ws + AHI_OFF);
  u16*   A_lo    = (u16*)  (ws + ALO_OFF);
  int*   idx_arr = (int*)  (ws + IDX_OFF);
  float* g_arr   = (float*)(ws + G_OFF);

  // zero padded NHWC buffer (borders must be 0; ws is poisoned each call)
  hipMemsetAsync(xp, 0, (size_t)NB*HP*HP*C*sizeof(float), stream);

  conv_small  <<<576,  64,  0, stream>>>(x, w_p, w_ad, partial);
  reduce_small<<<1512, 256, 0, stream>>>(partial, b_p, b_ad, off_buf, ad2_buf);
  pad_pack    <<<1152, 256, 0, stream>>>(x, xp);
  pack_A      <<<2304, 256, 0, stream>>>(w_conv, A_hi, A_lo);
  make_taps   <<<648,  256, 0, stream>>>(off_buf, ad2_buf, idx_arr, g_arr);
  gemm_def    <<<576,  256, 0, stream>>>(A_hi, A_lo, xp, idx_arr, g_arr, out);
}